// Round 8
// baseline (120.784 us; speedup 1.0000x reference)
//
#include <hip/hip_runtime.h>
#include <math.h>

namespace {
constexpr int H  = 8;
constexpr int D  = 64;
constexpr int NB = 32;   // number of 64-blocks along T
constexpr int BS = 64;   // block size
constexpr int QST = 68;  // padded LDS stride (critical path)
}
#define FEPS 1e-6f

typedef unsigned short u16;
typedef unsigned int   u32;
typedef __attribute__((ext_vector_type(8))) short bf16x8;
typedef __attribute__((ext_vector_type(4))) float floatx4;

__device__ __forceinline__ u32 f2bf(float x) {
  union { float f; u32 u; } v; v.f = x;
  return (v.u + 0x7FFFu + ((v.u >> 16) & 1u)) >> 16;
}
__device__ __forceinline__ u32 pk2(float a, float b) { return f2bf(a) | (f2bf(b) << 16); }
#define ELU1(x) ((x) > 0.f ? (x) + 1.f : expf(x))
// XOR swizzle at 8-ushort granularity: row-major [64][64] bf16 tile
#define SWZ(row, kblk) ((row)*64 + (((kblk) ^ ((row)&7))*8))

// ---------------- Kernel P: fused prologue ----------------
// blocks 0..255  : kvT[c][d] = bf16((elu(k)+1)^T v), k_sum (f32), krep (f64 mean of k)
// blocks 256..511: qrep (f64 block mean of q)
__global__ __launch_bounds__(256) void prep_kernel(const float* __restrict__ q,
                                                   const float* __restrict__ k,
                                                   const float* __restrict__ v,
                                                   u16* __restrict__ kvt16,
                                                   float* __restrict__ ksum,
                                                   double* __restrict__ qrep,
                                                   double* __restrict__ krep) {
  __shared__ float smem[3*BS*D];          // 48 KB
  int bid = blockIdx.x;
  int tid = threadIdx.x;
  if (bid >= 256) {
    // ---- q block means ----
    double* qred = (double*)smem;
    int r = bid - 256;                    // h*NB + bi
    int h = r >> 5, bi = r & 31;
    int d = tid & 63, quarter = tid >> 6;
    double s = 0.0;
    for (int t = quarter*16; t < quarter*16 + 16; ++t)
      s += (double)q[((bi*BS + t)*H + h)*D + d];
    qred[quarter*64 + d] = s;
    __syncthreads();
    if (tid < 64)
      qrep[r*D + tid] = (qred[tid] + qred[64+tid] + qred[128+tid] + qred[192+tid]) * (1.0/64.0);
    return;
  }
  // ---- kv path ----
  float* kf   = smem;                     // [s][d] elu(k)+1
  float* vv   = smem + BS*D;              // [s][c]
  float* kraw = smem + 2*BS*D;            // [s][d] raw k
  int h = bid >> 5, ki = bid & 31;
  int sr = tid >> 2, cgp = tid & 3;
  const float4* kb = (const float4*)(k + ((ki*BS + sr)*H + h)*D);
  const float4* vb = (const float4*)(v + ((ki*BS + sr)*H + h)*D);
#pragma unroll
  for (int m = 0; m < 4; ++m) {
    float4 kk = kb[cgp*4 + m];
    float4 vx = vb[cgp*4 + m];
    int c = cgp*16 + m*4;
    *(float4*)&kraw[sr*D + c] = kk;
    kf[sr*D + c + 0] = ELU1(kk.x);
    kf[sr*D + c + 1] = ELU1(kk.y);
    kf[sr*D + c + 2] = ELU1(kk.z);
    kf[sr*D + c + 3] = ELU1(kk.w);
    *(float4*)&vv[sr*D + c] = vx;
  }
  __syncthreads();
  // thread owns (c = tid&63, d0 = (tid>>6)*16): kvT[c][d0..d0+15]
  int c = tid & 63, dg = tid >> 6, d0 = dg*16;
  float acc[16];
#pragma unroll
  for (int j = 0; j < 16; ++j) acc[j] = 0.f;
#pragma unroll 4
  for (int s2 = 0; s2 < BS; ++s2) {
    float vval = vv[s2*D + c];
    const float4* kr = (const float4*)&kf[s2*D + d0];
    float4 a0 = kr[0], a1 = kr[1], a2 = kr[2], a3 = kr[3];
    acc[0]  += vval*a0.x; acc[1]  += vval*a0.y; acc[2]  += vval*a0.z; acc[3]  += vval*a0.w;
    acc[4]  += vval*a1.x; acc[5]  += vval*a1.y; acc[6]  += vval*a1.z; acc[7]  += vval*a1.w;
    acc[8]  += vval*a2.x; acc[9]  += vval*a2.y; acc[10] += vval*a2.z; acc[11] += vval*a2.w;
    acc[12] += vval*a3.x; acc[13] += vval*a3.y; acc[14] += vval*a3.z; acc[15] += vval*a3.w;
  }
  // write bf16 (same rounding main applies — numerically identical downstream)
  u16* op = kvt16 + (size_t)bid*4096 + c*64 + d0;
  uint4 P0, P1;
  P0.x = pk2(acc[0],acc[1]);   P0.y = pk2(acc[2],acc[3]);
  P0.z = pk2(acc[4],acc[5]);   P0.w = pk2(acc[6],acc[7]);
  P1.x = pk2(acc[8],acc[9]);   P1.y = pk2(acc[10],acc[11]);
  P1.z = pk2(acc[12],acc[13]); P1.w = pk2(acc[14],acc[15]);
  *(uint4*)(op + 0) = P0;
  *(uint4*)(op + 8) = P1;
  if (dg == 0) {
    float ks = 0.f;
    for (int s2 = 0; s2 < BS; ++s2) ks += kf[s2*D + c];
    ksum[bid*D + c] = ks;
    double m = 0.0;
    for (int s2 = 0; s2 < BS; ++s2) m += (double)kraw[s2*D + c];
    krep[bid*D + c] = m * (1.0/64.0);
  }
}

// ---------------- Kernel B: bscores + per-row stats (32 blocks) ----------------
__global__ __launch_bounds__(256) void bscore_stats_kernel(const double* __restrict__ qrep,
                                                           const double* __restrict__ krep,
                                                           double* __restrict__ rowmin,
                                                           double* __restrict__ rowmax,
                                                           double* __restrict__ rowvar) {
  __shared__ double qs[8*64];     // 4 KB
  __shared__ double ks[32*65];    // 16.6 KB, padded stride 65
  int b = blockIdx.x;
  int h = b >> 2;
  int r0 = b*8;
  int tid = threadIdx.x;
  for (int i = tid; i < 512; i += 256) qs[i] = qrep[(size_t)r0*64 + i];
  for (int i = tid; i < 2048; i += 256) ks[(i >> 6)*65 + (i & 63)] = krep[(size_t)h*2048 + i];
  __syncthreads();
  int lr = tid >> 5, ki = tid & 31;
  double s = 0.0;
  const double* qr = qs + lr*64;
  const double* kr = ks + ki*65;
#pragma unroll 16
  for (int d = 0; d < D; ++d) s += qr[d]*kr[d];
  double bs = s * 0.125;                 // / sqrt(64)
  double rmax = bs, rmin = bs;
#pragma unroll
  for (int m = 1; m < 32; m <<= 1) {
    rmax = fmax(rmax, __shfl_xor(rmax, m, 64));
    rmin = fmin(rmin, __shfl_xor(rmin, m, 64));
  }
  double e = exp(bs - rmax);
  double S = e, S2 = e*e;
#pragma unroll
  for (int m = 1; m < 32; m <<= 1) {
    S  += __shfl_xor(S,  m, 64);
    S2 += __shfl_xor(S2, m, 64);
  }
  if (ki == 0) {
    double invS = 1.0 / S;
    double sp = S * invS;
    double mu = sp * (1.0/32.0);
    double var = (S2*invS*invS - 2.0*mu*sp + 32.0*mu*mu) * (1.0/31.0);
    rowmin[r0 + lr] = rmin;
    rowmax[r0 + lr] = rmax;
    rowvar[r0 + lr] = var;
  }
}

// ---------------- Kernel D: main — flags + attention ----------------
// LDS float-offset map (marginal path), total 15488 floats = 61952 B:
//   [0,8)      redA (4 doubles)     [8,16)   redB (4 doubles)   [16,18) impS (1 double)
//   [1024,3072)  idens [64][32]
//   [3072,3136)  wsl  [64]
//   [3200,5248)  kslc [32][64]
//   [5248,7296)  qfb  u16[4096] swizzled
//   [7296,15488) kvS  u16[4*4096] (4 staged tiles)
// critical path reuses [0,4352) bufA, [4352,8704) bufB after the flag phase.
__global__ __launch_bounds__(256) void main_kernel(
    const float* __restrict__ q, const float* __restrict__ k, const float* __restrict__ v,
    const u16* __restrict__ kvt16, const float* __restrict__ ksum,
    const double* __restrict__ rowmin, const double* __restrict__ rowmax,
    const double* __restrict__ rowvar, float* __restrict__ out) {
  __shared__ __align__(16) float smem[15488];   // 61952 B
  int bid = blockIdx.x;                   // h*NB + qi
  int h = bid >> 5, qi = bid & 31;
  int tid = threadIdx.x;
  int row = tid >> 2, cgp = tid & 3, c0 = cgp*16;
  int lane = tid & 63;
  int wid = tid >> 6;

  float* idens = smem + 1024;
  float* wsl   = smem + 3072;
  float* kslc  = smem + 3200;
  u16*   qfb   = (u16*)(smem + 5248);
  u16*   kvS   = (u16*)(smem + 7296);

  // ===== pre-flag prefetch (regions disjoint from flag-phase buffers) =====
  // stage kslc
  {
    const float4* kss = (const float4*)(ksum + (size_t)(h*NB)*D);
    for (int i = tid; i < NB*16; i += 256) ((float4*)kslc)[i] = kss[i];
  }
  // load q row, compute qf, store bf16 A tile
  float qf[16];
  {
    const float4* qp = (const float4*)(q + ((qi*BS + row)*H + h)*D + c0);
    float4 q0 = qp[0], q1 = qp[1], q2 = qp[2], q3 = qp[3];
    qf[0]=ELU1(q0.x); qf[1]=ELU1(q0.y); qf[2]=ELU1(q0.z); qf[3]=ELU1(q0.w);
    qf[4]=ELU1(q1.x); qf[5]=ELU1(q1.y); qf[6]=ELU1(q1.z); qf[7]=ELU1(q1.w);
    qf[8]=ELU1(q2.x); qf[9]=ELU1(q2.y); qf[10]=ELU1(q2.z); qf[11]=ELU1(q2.w);
    qf[12]=ELU1(q3.x); qf[13]=ELU1(q3.y); qf[14]=ELU1(q3.z); qf[15]=ELU1(q3.w);
    uint4 p0, p1;
    p0.x = pk2(qf[0],qf[1]);  p0.y = pk2(qf[2],qf[3]);
    p0.z = pk2(qf[4],qf[5]);  p0.w = pk2(qf[6],qf[7]);
    p1.x = pk2(qf[8],qf[9]);  p1.y = pk2(qf[10],qf[11]);
    p1.z = pk2(qf[12],qf[13]); p1.w = pk2(qf[14],qf[15]);
    *(uint4*)&qfb[SWZ(row, cgp*2)]     = p0;
    *(uint4*)&qfb[SWZ(row, cgp*2 + 1)] = p1;
  }
  // prefetch kv tiles 0..3 (flag-phase latency hides these)
  const u16* kvbase = kvt16 + (size_t)(h*NB)*4096 + (size_t)row*64 + c0;
  uint4 pu0[4], pu1[4];
#pragma unroll
  for (int t = 0; t < 4; ++t) {
    const u16* p = kvbase + (size_t)t*4096;
    pu0[t] = *(const uint4*)(p);
    pu1[t] = *(const uint4*)(p + 8);
  }

  // ===== flag phase (shfl reductions, 4 barriers; min/max exact under reorder) =====
  int flag;
  {
    double* redA = (double*)smem;
    double* redB = (double*)(smem + 8);
    double* impS = (double*)(smem + 16);
    double x = rowmin[tid];
#pragma unroll
    for (int m = 1; m < 64; m <<= 1) x = fmin(x, __shfl_xor(x, m, 64));
    if (lane == 0) redA[wid] = x;
    __syncthreads();
    double gmin = fmin(fmin(redA[0], redA[1]), fmin(redA[2], redA[3]));
    double rng = rowmax[tid] - gmin;
    if (rng < 1e-6) rng = 1e-6;             // jnp.maximum(max - min, EPS)
    double imp = rowvar[tid] * rng;
    __syncthreads();                        // redA reads done before overwrite
    if (tid == bid) impS[0] = imp;
    double a = imp, b2 = imp;
#pragma unroll
    for (int m = 1; m < 64; m <<= 1) {
      a  = fmin(a,  __shfl_xor(a,  m, 64));
      b2 = fmax(b2, __shfl_xor(b2, m, 64));
    }
    if (lane == 0) { redA[wid] = a; redB[wid] = b2; }
    __syncthreads();
    double imin = fmin(fmin(redA[0], redA[1]), fmin(redA[2], redA[3]));
    double imax = fmax(fmax(redB[0], redB[1]), fmax(redB[2], redB[3]));
    double impn = (impS[0] - imin) / (imax - imin + 1e-6);
    flag = (impn >= 0.5) ? 2 : ((impn <= 0.01) ? 0 : 1);
    __syncthreads();                        // smem free for reuse
  }

  if (flag == 1) {
    // ---- marginal: linear (ELU+1) attention via bf16 MFMA, 4-tile rounds ----
    int w = tid >> 6, m = lane & 15, quad = lane >> 4;
    bf16x8 aLo = *(const bf16x8*)&qfb[SWZ(w*16 + m, quad)];
    bf16x8 aHi = *(const bf16x8*)&qfb[SWZ(w*16 + m, 4 + quad)];
    int rbase = w*16 + quad*4;

    // den[row][ki] exact f32: partial over 16 cols + shfl reduce over 4 lanes
    {
      float wloc = 0.f;
      for (int ki = 0; ki < NB; ++ki) {
        const float4* ks4 = (const float4*)&kslc[ki*64 + c0];
        float4 k0 = ks4[0], k1 = ks4[1], k2 = ks4[2], k3 = ks4[3];
        float pd = qf[0]*k0.x + qf[1]*k0.y + qf[2]*k0.z + qf[3]*k0.w
                 + qf[4]*k1.x + qf[5]*k1.y + qf[6]*k1.z + qf[7]*k1.w
                 + qf[8]*k2.x + qf[9]*k2.y + qf[10]*k2.z + qf[11]*k2.w
                 + qf[12]*k3.x + qf[13]*k3.y + qf[14]*k3.z + qf[15]*k3.w;
        pd += __shfl_xor(pd, 1, 64);
        pd += __shfl_xor(pd, 2, 64);
        float den = pd + FEPS;
        if (cgp == 0) idens[row*32 + ki] = 1.0f / den;
        wloc += den;
      }
      if (cgp == 0) wsl[row] = wloc;
    }
    // store prefetched tiles 0..3
#pragma unroll
    for (int t = 0; t < 4; ++t) {
      *(uint4*)&kvS[t*4096 + SWZ(row, cgp*2)]     = pu0[t];
      *(uint4*)&kvS[t*4096 + SWZ(row, cgp*2 + 1)] = pu1[t];
    }
    __syncthreads();

    float acc[16];
#pragma unroll
    for (int j = 0; j < 16; ++j) acc[j] = 0.f;

    for (int rd = 0; rd < 8; ++rd) {
      // issue next round's loads (overlaps this round's MFMA)
      uint4 nu0[4], nu1[4];
      if (rd < 7) {
#pragma unroll
        for (int t = 0; t < 4; ++t) {
          const u16* p = kvbase + (size_t)((rd+1)*4 + t)*4096;
          nu0[t] = *(const uint4*)(p);
          nu1[t] = *(const uint4*)(p + 8);
        }
      }
#pragma unroll
      for (int kk = 0; kk < 4; ++kk) {
        int ki = rd*4 + kk;
        const u16* kb = kvS + kk*4096;
        float i0 = idens[(rbase + 0)*32 + ki];
        float i1 = idens[(rbase + 1)*32 + ki];
        float i2 = idens[(rbase + 2)*32 + ki];
        float i3 = idens[(rbase + 3)*32 + ki];
        floatx4 zz = {0.f, 0.f, 0.f, 0.f};
#pragma unroll
        for (int t = 0; t < 4; ++t) {
          bf16x8 bLo = *(const bf16x8*)&kb[SWZ(t*16 + m, quad)];
          bf16x8 bHi = *(const bf16x8*)&kb[SWZ(t*16 + m, 4 + quad)];
          floatx4 c4 = __builtin_amdgcn_mfma_f32_16x16x32_bf16(aLo, bLo, zz, 0, 0, 0);
          c4 = __builtin_amdgcn_mfma_f32_16x16x32_bf16(aHi, bHi, c4, 0, 0, 0);
          acc[t*4+0] += c4[0]*i0;
          acc[t*4+1] += c4[1]*i1;
          acc[t*4+2] += c4[2]*i2;
          acc[t*4+3] += c4[3]*i3;
        }
      }
      __syncthreads();                      // reads of this round done
      if (rd < 7) {
#pragma unroll
        for (int t = 0; t < 4; ++t) {
          *(uint4*)&kvS[t*4096 + SWZ(row, cgp*2)]     = nu0[t];
          *(uint4*)&kvS[t*4096 + SWZ(row, cgp*2 + 1)] = nu1[t];
        }
      }
      __syncthreads();                      // stores visible
    }
#pragma unroll
    for (int r = 0; r < 4; ++r) {
      float wd = 1.0f / (wsl[rbase + r] + FEPS);
      float* op = out + ((qi*BS + rbase + r)*H + h)*D + m;
#pragma unroll
      for (int t = 0; t < 4; ++t) op[t*16] = acc[t*4+r]*wd;
    }
    return;
  }

  // ---- critical / negligible: f32 path ----
  float* bufA = smem;                 // [QST*64]
  float* bufB = smem + 4352;          // [QST*64]
  float acc[16];
#pragma unroll
  for (int j = 0; j < 16; ++j) acc[j] = 0.f;
  float wsum = 0.f;

  if (flag == 2) {
    const float4* qp = (const float4*)(q + ((qi*BS + row)*H + h)*D);
#pragma unroll
    for (int mm = 0; mm < 4; ++mm) {
      float4 qq = qp[cgp*4 + mm];
      int c = c0 + mm*4;
      bufA[row*QST + c + 0] = qq.x*0.125f;
      bufA[row*QST + c + 1] = qq.y*0.125f;
      bufA[row*QST + c + 2] = qq.z*0.125f;
      bufA[row*QST + c + 3] = qq.w*0.125f;
    }
    __syncthreads();
    for (int ki = 0; ki < NB; ++ki) {
      const float4* kp = (const float4*)(k + ((ki*BS + row)*H + h)*D);
#pragma unroll
      for (int mm = 0; mm < 4; ++mm)
        *(float4*)&bufB[row*QST + c0 + mm*4] = kp[cgp*4 + mm];
      __syncthreads();
      float sc[16];
#pragma unroll
      for (int j = 0; j < 16; ++j) sc[j] = 0.f;
      for (int d = 0; d < D; ++d) {
        float a = bufA[row*QST + d];
#pragma unroll
        for (int j = 0; j < 16; ++j)
          sc[j] += a * bufB[(c0 + j)*QST + d];
      }
      float mx = sc[0];
#pragma unroll
      for (int j = 1; j < 16; ++j) mx = fmaxf(mx, sc[j]);
      mx = fmaxf(mx, __shfl_xor(mx, 1, 64));
      mx = fmaxf(mx, __shfl_xor(mx, 2, 64));
      float es = 0.f;
      float p[16];
#pragma unroll
      for (int j = 0; j < 16; ++j) { p[j] = expf(sc[j] - mx); es += p[j]; }
      es += __shfl_xor(es, 1, 64);
      es += __shfl_xor(es, 2, 64);
      float inv = 1.0f / es;
#pragma unroll
      for (int j = 0; j < 16; ++j) p[j] *= inv;
      wsum += es * inv;
      __syncthreads();
      const float4* vp = (const float4*)(v + ((ki*BS + row)*H + h)*D);
#pragma unroll
      for (int mm = 0; mm < 4; ++mm)
        *(float4*)&bufB[row*QST + c0 + mm*4] = vp[cgp*4 + mm];
      __syncthreads();
      for (int s2 = 0; s2 < BS; ++s2) {
        int g = s2 >> 4, jj = s2 & 15;
        float pv = __shfl(p[jj], (lane & ~3) | g, 64);
        const float4* vr = (const float4*)&bufB[s2*QST + c0];
        float4 a0 = vr[0], a1 = vr[1], a2 = vr[2], a3 = vr[3];
        acc[0]  += pv*a0.x; acc[1]  += pv*a0.y; acc[2]  += pv*a0.z; acc[3]  += pv*a0.w;
        acc[4]  += pv*a1.x; acc[5]  += pv*a1.y; acc[6]  += pv*a1.z; acc[7]  += pv*a1.w;
        acc[8]  += pv*a2.x; acc[9]  += pv*a2.y; acc[10] += pv*a2.z; acc[11] += pv*a2.w;
        acc[12] += pv*a3.x; acc[13] += pv*a3.y; acc[14] += pv*a3.z; acc[15] += pv*a3.w;
      }
      __syncthreads();
    }
  }
  float wd = 1.0f / (wsum + FEPS);
  float* op = out + ((qi*BS + row)*H + h)*D + c0;
  *(float4*)(op + 0)  = make_float4(acc[0]*wd,  acc[1]*wd,  acc[2]*wd,  acc[3]*wd);
  *(float4*)(op + 4)  = make_float4(acc[4]*wd,  acc[5]*wd,  acc[6]*wd,  acc[7]*wd);
  *(float4*)(op + 8)  = make_float4(acc[8]*wd,  acc[9]*wd,  acc[10]*wd, acc[11]*wd);
  *(float4*)(op + 12) = make_float4(acc[12]*wd, acc[13]*wd, acc[14]*wd, acc[15]*wd);
}

extern "C" void kernel_launch(void* const* d_in, const int* in_sizes, int n_in,
                              void* d_out, int out_size, void* d_ws, size_t ws_size,
                              hipStream_t stream) {
  const float* q = (const float*)d_in[0];
  const float* k = (const float*)d_in[1];
  const float* v = (const float*)d_in[2];
  float* out = (float*)d_out;
  char* ws = (char*)d_ws;
  // workspace layout (16B-aligned)
  u16*    kvw  = (u16*)   (ws + 0);         // 256*4096 u16 (2 MB)
  float*  ksw  = (float*) (ws + 2097152);   // 16384 floats
  double* krep = (double*)(ws + 2162688);   // 16384 doubles
  double* qrep = (double*)(ws + 2293760);   // 16384 doubles
  double* rmn  = (double*)(ws + 2424832);   // 256 doubles
  double* rmx  = (double*)(ws + 2426880);   // 256 doubles
  double* rvr  = (double*)(ws + 2428928);   // 256 doubles

  prep_kernel<<<512, 256, 0, stream>>>(q, k, v, kvw, ksw, qrep, krep);
  bscore_stats_kernel<<<32, 256, 0, stream>>>(qrep, krep, rmn, rmx, rvr);
  main_kernel<<<256, 256, 0, stream>>>(q, k, v, kvw, ksw, rmn, rmx, rvr, out);
}

// Round 9
// 96.936 us; speedup vs baseline: 1.2460x; 1.2460x over previous
//
#include <hip/hip_runtime.h>
#include <math.h>

namespace {
constexpr int H  = 8;
constexpr int D  = 64;
constexpr int NB = 32;   // number of 64-blocks along T
constexpr int BS = 64;   // block size
constexpr int QST = 68;  // padded LDS stride (critical path)
}
#define FEPS 1e-6f

typedef unsigned short u16;
typedef unsigned int   u32;
typedef __attribute__((ext_vector_type(8))) short bf16x8;
typedef __attribute__((ext_vector_type(4))) float floatx4;

__device__ __forceinline__ u32 f2bf(float x) {
  union { float f; u32 u; } v; v.f = x;
  return (v.u + 0x7FFFu + ((v.u >> 16) & 1u)) >> 16;
}
__device__ __forceinline__ u32 pk2(float a, float b) { return f2bf(a) | (f2bf(b) << 16); }
#define ELU1(x) ((x) > 0.f ? (x) + 1.f : expf(x))
// XOR swizzle at 8-ushort granularity: row-major [64][64] bf16 tile
#define SWZ(row, kblk) ((row)*64 + (((kblk) ^ ((row)&7))*8))

// ---------------- Kernel P: fused prologue ----------------
// blocks 0..255  : kvT[c][d] = bf16((elu(k)+1)^T v), k_sum (f32), krep (f64 mean of k)
// blocks 256..511: qrep (f64 block mean of q)
__global__ __launch_bounds__(256) void prep_kernel(const float* __restrict__ q,
                                                   const float* __restrict__ k,
                                                   const float* __restrict__ v,
                                                   u16* __restrict__ kvt16,
                                                   float* __restrict__ ksum,
                                                   double* __restrict__ qrep,
                                                   double* __restrict__ krep) {
  __shared__ float smem[3*BS*D];          // 48 KB
  int bid = blockIdx.x;
  int tid = threadIdx.x;
  if (bid >= 256) {
    // ---- q block means ----
    double* qred = (double*)smem;
    int r = bid - 256;                    // h*NB + bi
    int h = r >> 5, bi = r & 31;
    int d = tid & 63, quarter = tid >> 6;
    double s = 0.0;
    for (int t = quarter*16; t < quarter*16 + 16; ++t)
      s += (double)q[((bi*BS + t)*H + h)*D + d];
    qred[quarter*64 + d] = s;
    __syncthreads();
    if (tid < 64)
      qrep[r*D + tid] = (qred[tid] + qred[64+tid] + qred[128+tid] + qred[192+tid]) * (1.0/64.0);
    return;
  }
  // ---- kv path ----
  float* kf   = smem;                     // [s][d] elu(k)+1
  float* vv   = smem + BS*D;              // [s][c]
  float* kraw = smem + 2*BS*D;            // [s][d] raw k
  int h = bid >> 5, ki = bid & 31;
  int sr = tid >> 2, cgp = tid & 3;
  const float4* kb = (const float4*)(k + ((ki*BS + sr)*H + h)*D);
  const float4* vb = (const float4*)(v + ((ki*BS + sr)*H + h)*D);
#pragma unroll
  for (int m = 0; m < 4; ++m) {
    float4 kk = kb[cgp*4 + m];
    float4 vx = vb[cgp*4 + m];
    int c = cgp*16 + m*4;
    *(float4*)&kraw[sr*D + c] = kk;
    kf[sr*D + c + 0] = ELU1(kk.x);
    kf[sr*D + c + 1] = ELU1(kk.y);
    kf[sr*D + c + 2] = ELU1(kk.z);
    kf[sr*D + c + 3] = ELU1(kk.w);
    *(float4*)&vv[sr*D + c] = vx;
  }
  __syncthreads();
  // thread owns (c = tid&63, d0 = (tid>>6)*16): kvT[c][d0..d0+15]
  int c = tid & 63, dg = tid >> 6, d0 = dg*16;
  float acc[16];
#pragma unroll
  for (int j = 0; j < 16; ++j) acc[j] = 0.f;
#pragma unroll 4
  for (int s2 = 0; s2 < BS; ++s2) {
    float vval = vv[s2*D + c];
    const float4* kr = (const float4*)&kf[s2*D + d0];
    float4 a0 = kr[0], a1 = kr[1], a2 = kr[2], a3 = kr[3];
    acc[0]  += vval*a0.x; acc[1]  += vval*a0.y; acc[2]  += vval*a0.z; acc[3]  += vval*a0.w;
    acc[4]  += vval*a1.x; acc[5]  += vval*a1.y; acc[6]  += vval*a1.z; acc[7]  += vval*a1.w;
    acc[8]  += vval*a2.x; acc[9]  += vval*a2.y; acc[10] += vval*a2.z; acc[11] += vval*a2.w;
    acc[12] += vval*a3.x; acc[13] += vval*a3.y; acc[14] += vval*a3.z; acc[15] += vval*a3.w;
  }
  // write bf16 (same rounding main applies — numerically identical downstream)
  u16* op = kvt16 + (size_t)bid*4096 + c*64 + d0;
  uint4 P0, P1;
  P0.x = pk2(acc[0],acc[1]);   P0.y = pk2(acc[2],acc[3]);
  P0.z = pk2(acc[4],acc[5]);   P0.w = pk2(acc[6],acc[7]);
  P1.x = pk2(acc[8],acc[9]);   P1.y = pk2(acc[10],acc[11]);
  P1.z = pk2(acc[12],acc[13]); P1.w = pk2(acc[14],acc[15]);
  *(uint4*)(op + 0) = P0;
  *(uint4*)(op + 8) = P1;
  if (dg == 0) {
    float ks = 0.f;
    for (int s2 = 0; s2 < BS; ++s2) ks += kf[s2*D + c];
    ksum[bid*D + c] = ks;
    double m = 0.0;
    for (int s2 = 0; s2 < BS; ++s2) m += (double)kraw[s2*D + c];
    krep[bid*D + c] = m * (1.0/64.0);
  }
}

// ---------------- Kernel B: bscores + per-row stats (32 blocks) ----------------
__global__ __launch_bounds__(256) void bscore_stats_kernel(const double* __restrict__ qrep,
                                                           const double* __restrict__ krep,
                                                           double* __restrict__ rowmin,
                                                           double* __restrict__ rowmax,
                                                           double* __restrict__ rowvar) {
  __shared__ double qs[8*64];     // 4 KB
  __shared__ double ks[32*65];    // 16.6 KB, padded stride 65
  int b = blockIdx.x;
  int h = b >> 2;
  int r0 = b*8;
  int tid = threadIdx.x;
  for (int i = tid; i < 512; i += 256) qs[i] = qrep[(size_t)r0*64 + i];
  for (int i = tid; i < 2048; i += 256) ks[(i >> 6)*65 + (i & 63)] = krep[(size_t)h*2048 + i];
  __syncthreads();
  int lr = tid >> 5, ki = tid & 31;
  double s = 0.0;
  const double* qr = qs + lr*64;
  const double* kr = ks + ki*65;
#pragma unroll 16
  for (int d = 0; d < D; ++d) s += qr[d]*kr[d];
  double bs = s * 0.125;                 // / sqrt(64)
  double rmax = bs, rmin = bs;
#pragma unroll
  for (int m = 1; m < 32; m <<= 1) {
    rmax = fmax(rmax, __shfl_xor(rmax, m, 64));
    rmin = fmin(rmin, __shfl_xor(rmin, m, 64));
  }
  double e = exp(bs - rmax);
  double S = e, S2 = e*e;
#pragma unroll
  for (int m = 1; m < 32; m <<= 1) {
    S  += __shfl_xor(S,  m, 64);
    S2 += __shfl_xor(S2, m, 64);
  }
  if (ki == 0) {
    double invS = 1.0 / S;
    double sp = S * invS;
    double mu = sp * (1.0/32.0);
    double var = (S2*invS*invS - 2.0*mu*sp + 32.0*mu*mu) * (1.0/31.0);
    rowmin[r0 + lr] = rmin;
    rowmax[r0 + lr] = rmax;
    rowvar[r0 + lr] = var;
  }
}

// ---------------- Kernel D: main — flags (shfl) + attention (R7 structure) ----------------
__global__ __launch_bounds__(256) void main_kernel(
    const float* __restrict__ q, const float* __restrict__ k, const float* __restrict__ v,
    const u16* __restrict__ kvt16, const float* __restrict__ ksum,
    const double* __restrict__ rowmin, const double* __restrict__ rowmax,
    const double* __restrict__ rowvar, float* __restrict__ out) {
  __shared__ __align__(16) float smem[10304];   // 41216 B
  int bid = blockIdx.x;                   // h*NB + qi
  int h = bid >> 5, qi = bid & 31;
  int tid = threadIdx.x;
  int row = tid >> 2, cgp = tid & 3, c0 = cgp*16;
  int lane = tid & 63;
  int wid = tid >> 6;

  // ===== flag phase: shfl reductions, 3 barriers (min/max exact under reorder) =====
  int flag;
  {
    double* redA = (double*)smem;           // 4 doubles
    double* redB = (double*)(smem + 8);     // 4 doubles
    double* impS = (double*)(smem + 16);    // 1 double
    double x = rowmin[tid];
    double rmx2 = rowmax[tid];
    double rvr2 = rowvar[tid];
#pragma unroll
    for (int m = 1; m < 64; m <<= 1) x = fmin(x, __shfl_xor(x, m, 64));
    if (lane == 0) redA[wid] = x;
    __syncthreads();
    double gmin = fmin(fmin(redA[0], redA[1]), fmin(redA[2], redA[3]));
    double rng = rmx2 - gmin;
    if (rng < 1e-6) rng = 1e-6;             // jnp.maximum(max - min, EPS)
    double imp = rvr2 * rng;
    __syncthreads();                        // redA reads done before overwrite
    if (tid == bid) impS[0] = imp;
    double a = imp, b2 = imp;
#pragma unroll
    for (int m = 1; m < 64; m <<= 1) {
      a  = fmin(a,  __shfl_xor(a,  m, 64));
      b2 = fmax(b2, __shfl_xor(b2, m, 64));
    }
    if (lane == 0) { redA[wid] = a; redB[wid] = b2; }
    __syncthreads();
    double imin = fmin(fmin(redA[0], redA[1]), fmin(redA[2], redA[3]));
    double imax = fmax(fmax(redB[0], redB[1]), fmax(redB[2], redB[3]));
    double impn = (impS[0] - imin) / (imax - imin + 1e-6);
    flag = (impn >= 0.5) ? 2 : ((impn <= 0.01) ? 0 : 1);
    __syncthreads();                        // smem free for reuse
  }

  if (flag == 1) {
    // ---- marginal: linear (ELU+1) attention via bf16 MFMA, double-buffered (R7) ----
    u16*  qfb  = (u16*)smem;              // [64][64] bf16, swizzled          (8 KB)
    u16*  kvb  = (u16*)(smem + 2048);     // 2 x [64][64] bf16, swizzled      (16 KB)
    float* idens = smem + 6144;           // [64][32] 1/den                   (8 KB)
    float* wsl   = smem + 8192;           // [64] sum of den
    float* kslc  = smem + 8256;           // [32][64] k_sum                   (8 KB)

    {
      const float4* kss = (const float4*)(ksum + (size_t)(h*NB)*D);
      for (int i = tid; i < NB*16; i += 256) ((float4*)kslc)[i] = kss[i];
    }
    float qf[16];
    {
      const float4* qp = (const float4*)(q + ((qi*BS + row)*H + h)*D + c0);
      float4 q0 = qp[0], q1 = qp[1], q2 = qp[2], q3 = qp[3];
      qf[0]=ELU1(q0.x); qf[1]=ELU1(q0.y); qf[2]=ELU1(q0.z); qf[3]=ELU1(q0.w);
      qf[4]=ELU1(q1.x); qf[5]=ELU1(q1.y); qf[6]=ELU1(q1.z); qf[7]=ELU1(q1.w);
      qf[8]=ELU1(q2.x); qf[9]=ELU1(q2.y); qf[10]=ELU1(q2.z); qf[11]=ELU1(q2.w);
      qf[12]=ELU1(q3.x); qf[13]=ELU1(q3.y); qf[14]=ELU1(q3.z); qf[15]=ELU1(q3.w);
      uint4 p0, p1;
      p0.x = pk2(qf[0],qf[1]);  p0.y = pk2(qf[2],qf[3]);
      p0.z = pk2(qf[4],qf[5]);  p0.w = pk2(qf[6],qf[7]);
      p1.x = pk2(qf[8],qf[9]);  p1.y = pk2(qf[10],qf[11]);
      p1.z = pk2(qf[12],qf[13]); p1.w = pk2(qf[14],qf[15]);
      *(uint4*)&qfb[SWZ(row, cgp*2)]     = p0;
      *(uint4*)&qfb[SWZ(row, cgp*2 + 1)] = p1;
    }
    // prefetch bf16 kv tile 0 (16 u16 = 32 B per thread)
    const u16* kvbase = kvt16 + (size_t)(h*NB)*4096 + (size_t)row*64 + c0;
    uint4 u0, u1;
    u0 = *(const uint4*)(kvbase + 0);
    u1 = *(const uint4*)(kvbase + 8);
    __syncthreads();
    // den[row][ki] exact f32: partial over 16 cols + shfl reduce over 4 lanes
    {
      float wloc = 0.f;
      for (int ki = 0; ki < NB; ++ki) {
        float pd = 0.f;
#pragma unroll
        for (int j = 0; j < 16; ++j) pd += qf[j] * kslc[ki*64 + c0 + j];
        pd += __shfl_xor(pd, 1, 64);
        pd += __shfl_xor(pd, 2, 64);
        float den = pd + FEPS;
        if (cgp == 0) idens[row*32 + ki] = 1.0f / den;
        wloc += den;
      }
      if (cgp == 0) wsl[row] = wloc;
    }
    // store tile 0 into buffer 0
    *(uint4*)&kvb[SWZ(row, cgp*2)]     = u0;
    *(uint4*)&kvb[SWZ(row, cgp*2 + 1)] = u1;

    int w = tid >> 6, m = lane & 15, quad = lane >> 4;
    bf16x8 aLo = *(const bf16x8*)&qfb[SWZ(w*16 + m, quad)];
    bf16x8 aHi = *(const bf16x8*)&qfb[SWZ(w*16 + m, 4 + quad)];
    int rbase = w*16 + quad*4;
    float acc[16];
#pragma unroll
    for (int j = 0; j < 16; ++j) acc[j] = 0.f;

    for (int ki = 0; ki < NB; ++ki) {
      if (ki + 1 < NB) {
        const u16* kvp = kvbase + (size_t)(ki+1)*4096;
        u0 = *(const uint4*)(kvp + 0);
        u1 = *(const uint4*)(kvp + 8);
      }
      __syncthreads();                    // tile ki visible; reads of ki-1 done
      const u16* kb = kvb + (ki & 1)*4096;
      float i0 = idens[(rbase + 0)*32 + ki];
      float i1 = idens[(rbase + 1)*32 + ki];
      float i2 = idens[(rbase + 2)*32 + ki];
      float i3 = idens[(rbase + 3)*32 + ki];
      floatx4 zz = {0.f, 0.f, 0.f, 0.f};
#pragma unroll
      for (int t = 0; t < 4; ++t) {
        bf16x8 bLo = *(const bf16x8*)&kb[SWZ(t*16 + m, quad)];
        bf16x8 bHi = *(const bf16x8*)&kb[SWZ(t*16 + m, 4 + quad)];
        floatx4 c4 = __builtin_amdgcn_mfma_f32_16x16x32_bf16(aLo, bLo, zz, 0, 0, 0);
        c4 = __builtin_amdgcn_mfma_f32_16x16x32_bf16(aHi, bHi, c4, 0, 0, 0);
        acc[t*4+0] += c4[0]*i0;
        acc[t*4+1] += c4[1]*i1;
        acc[t*4+2] += c4[2]*i2;
        acc[t*4+3] += c4[3]*i3;
      }
      if (ki + 1 < NB) {
        u16* kw = kvb + ((ki+1) & 1)*4096;
        *(uint4*)&kw[SWZ(row, cgp*2)]     = u0;
        *(uint4*)&kw[SWZ(row, cgp*2 + 1)] = u1;
      }
    }
#pragma unroll
    for (int r = 0; r < 4; ++r) {
      float wd = 1.0f / (wsl[rbase + r] + FEPS);
      float* op = out + ((qi*BS + rbase + r)*H + h)*D + m;
#pragma unroll
      for (int t = 0; t < 4; ++t) op[t*16] = acc[t*4+r]*wd;
    }
    return;
  }

  // ---- critical / negligible: f32 path ----
  float* bufA = smem;                 // [QST*64]
  float* bufB = smem + 4352;          // [QST*64]
  float acc[16];
#pragma unroll
  for (int j = 0; j < 16; ++j) acc[j] = 0.f;
  float wsum = 0.f;

  if (flag == 2) {
    const float4* qp = (const float4*)(q + ((qi*BS + row)*H + h)*D);
#pragma unroll
    for (int mm = 0; mm < 4; ++mm) {
      float4 qq = qp[cgp*4 + mm];
      int c = c0 + mm*4;
      bufA[row*QST + c + 0] = qq.x*0.125f;
      bufA[row*QST + c + 1] = qq.y*0.125f;
      bufA[row*QST + c + 2] = qq.z*0.125f;
      bufA[row*QST + c + 3] = qq.w*0.125f;
    }
    __syncthreads();
    for (int ki = 0; ki < NB; ++ki) {
      const float4* kp = (const float4*)(k + ((ki*BS + row)*H + h)*D);
#pragma unroll
      for (int mm = 0; mm < 4; ++mm)
        *(float4*)&bufB[row*QST + c0 + mm*4] = kp[cgp*4 + mm];
      __syncthreads();
      float sc[16];
#pragma unroll
      for (int j = 0; j < 16; ++j) sc[j] = 0.f;
      for (int d = 0; d < D; ++d) {
        float a = bufA[row*QST + d];
#pragma unroll
        for (int j = 0; j < 16; ++j)
          sc[j] += a * bufB[(c0 + j)*QST + d];
      }
      float mx = sc[0];
#pragma unroll
      for (int j = 1; j < 16; ++j) mx = fmaxf(mx, sc[j]);
      mx = fmaxf(mx, __shfl_xor(mx, 1, 64));
      mx = fmaxf(mx, __shfl_xor(mx, 2, 64));
      float es = 0.f;
      float p[16];
#pragma unroll
      for (int j = 0; j < 16; ++j) { p[j] = expf(sc[j] - mx); es += p[j]; }
      es += __shfl_xor(es, 1, 64);
      es += __shfl_xor(es, 2, 64);
      float inv = 1.0f / es;
#pragma unroll
      for (int j = 0; j < 16; ++j) p[j] *= inv;
      wsum += es * inv;
      __syncthreads();
      const float4* vp = (const float4*)(v + ((ki*BS + row)*H + h)*D);
#pragma unroll
      for (int mm = 0; mm < 4; ++mm)
        *(float4*)&bufB[row*QST + c0 + mm*4] = vp[cgp*4 + mm];
      __syncthreads();
      for (int s2 = 0; s2 < BS; ++s2) {
        int g = s2 >> 4, jj = s2 & 15;
        float pv = __shfl(p[jj], (lane & ~3) | g, 64);
        const float4* vr = (const float4*)&bufB[s2*QST + c0];
        float4 a0 = vr[0], a1 = vr[1], a2 = vr[2], a3 = vr[3];
        acc[0]  += pv*a0.x; acc[1]  += pv*a0.y; acc[2]  += pv*a0.z; acc[3]  += pv*a0.w;
        acc[4]  += pv*a1.x; acc[5]  += pv*a1.y; acc[6]  += pv*a1.z; acc[7]  += pv*a1.w;
        acc[8]  += pv*a2.x; acc[9]  += pv*a2.y; acc[10] += pv*a2.z; acc[11] += pv*a2.w;
        acc[12] += pv*a3.x; acc[13] += pv*a3.y; acc[14] += pv*a3.z; acc[15] += pv*a3.w;
      }
      __syncthreads();
    }
  }
  float wd = 1.0f / (wsum + FEPS);
  float* op = out + ((qi*BS + row)*H + h)*D + c0;
  *(float4*)(op + 0)  = make_float4(acc[0]*wd,  acc[1]*wd,  acc[2]*wd,  acc[3]*wd);
  *(float4*)(op + 4)  = make_float4(acc[4]*wd,  acc[5]*wd,  acc[6]*wd,  acc[7]*wd);
  *(float4*)(op + 8)  = make_float4(acc[8]*wd,  acc[9]*wd,  acc[10]*wd, acc[11]*wd);
  *(float4*)(op + 12) = make_float4(acc[12]*wd, acc[13]*wd, acc[14]*wd, acc[15]*wd);
}

extern "C" void kernel_launch(void* const* d_in, const int* in_sizes, int n_in,
                              void* d_out, int out_size, void* d_ws, size_t ws_size,
                              hipStream_t stream) {
  const float* q = (const float*)d_in[0];
  const float* k = (const float*)d_in[1];
  const float* v = (const float*)d_in[2];
  float* out = (float*)d_out;
  char* ws = (char*)d_ws;
  // workspace layout (16B-aligned)
  u16*    kvw  = (u16*)   (ws + 0);         // 256*4096 u16 (2 MB)
  float*  ksw  = (float*) (ws + 2097152);   // 16384 floats
  double* krep = (double*)(ws + 2162688);   // 16384 doubles
  double* qrep = (double*)(ws + 2293760);   // 16384 doubles
  double* rmn  = (double*)(ws + 2424832);   // 256 doubles
  double* rmx  = (double*)(ws + 2426880);   // 256 doubles
  double* rvr  = (double*)(ws + 2428928);   // 256 doubles

  prep_kernel<<<512, 256, 0, stream>>>(q, k, v, kvw, ksw, qrep, krep);
  bscore_stats_kernel<<<32, 256, 0, stream>>>(qrep, krep, rmn, rmx, rvr);
  main_kernel<<<256, 256, 0, stream>>>(q, k, v, kvw, ksw, rmn, rmx, rvr, out);
}